// Round 17
// baseline (172.439 us; speedup 1.0000x reference)
//
#include <hip/hip_runtime.h>
#include <stdint.h>

typedef unsigned short u16;
typedef __bf16 bf16x8 __attribute__((ext_vector_type(8)));
typedef float f32x4 __attribute__((ext_vector_type(4)));

#define QSCALE (19.5f/1024.0f * 1.44269504088896340736f)
// float-magic Schraudolph: y = fma(s,128, 2^23*1.5 + 16250) -> low16(bits(y)) = bf16bits(exp2(s))
#define EXPMAGIC 12599162.0f

__device__ __forceinline__ u16 f2bf(float f){
  uint32_t u = __float_as_uint(f);
  return (u16)((u + 0x7FFFu + ((u >> 16) & 1u)) >> 16);   // RNE
}

__device__ __forceinline__ uint64_t cvt4(float4 f){
  union{ u16 u[4]; uint64_t v; } pk;
  pk.u[0]=f2bf(f.x); pk.u[1]=f2bf(f.y); pk.u[2]=f2bf(f.z); pk.u[3]=f2bf(f.w);
  return pk.v;
}

#define GLD_LDS16(g,l) __builtin_amdgcn_global_load_lds( \
    (const __attribute__((address_space(1))) void*)(g),  \
    (__attribute__((address_space(3))) void*)(l), 16, 0, 0)

// ---------------- fused prep ----------------
__global__ __launch_bounds__(256) void k_prep(
    const float4* __restrict__ x,  const float4* __restrict__ Wq,
    const float4* __restrict__ Wk, const float4* __restrict__ Wv,
    const float4* __restrict__ Wo,
    const float4* __restrict__ bq, const float4* __restrict__ bk, const float4* __restrict__ bv,
    uint64_t* __restrict__ xb, uint64_t* __restrict__ wqkv, uint64_t* __restrict__ wob,
    float4* __restrict__ bqkv)
{
  const int NX = 2097152, NW = 262144;
  const int total = NX + 4*NW + 768;
  int i = blockIdx.x*256 + threadIdx.x;
  const int stride = gridDim.x*256;
  for (; i < total; i += stride){
    if (i < NX)             xb[i] = cvt4(x[i]);
    else if (i < NX+NW)     { int j = i-NX;      wqkv[j]      = cvt4(Wq[j]); }
    else if (i < NX+2*NW)   { int j = i-NX-NW;   wqkv[NW+j]   = cvt4(Wk[j]); }
    else if (i < NX+3*NW)   { int j = i-NX-2*NW; wqkv[2*NW+j] = cvt4(Wv[j]); }
    else if (i < NX+4*NW)   { int j = i-NX-3*NW; wob[j]       = cvt4(Wo[j]); }
    else {
      int j = i - NX - 4*NW;
      bqkv[j] = (j < 256) ? bq[j] : (j < 512 ? bk[j-256] : bv[j-512]);
    }
  }
}

// ---------------- 256x256 bf16 GEMM (QKV proj): 4 waves, wave-tile 128x128 ----------------
// BK=32, 3-ring (96KB), stage-2-ahead, counted vmcnt(8). MFMA:ds_read = 4:1 (64 MFMA,
// 16 b128 reads per wave per tile). acc[8][8] = 256 AGPRs; 1 wave/SIMD.
// Balanced swizzle: LDS[row][c] = global[row][c ^ ((row>>1)&3)].
__global__ __launch_bounds__(256, 1) void gemm256w(
    const u16* __restrict__ A, const u16* __restrict__ Bw,
    const float* __restrict__ bias,
    u16* __restrict__ q_ws, u16* __restrict__ k_ws, u16* __restrict__ v_ws)
{
  __shared__ u16 lds[3*16384];   // [buf:3][ A:256x32 | B:256x32 ] u16
  const int tid  = threadIdx.x;
  const int w    = tid >> 6, lane = tid & 63;
  const int wr   = w >> 1,  wc   = w & 1;
  const int g    = lane >> 4, c16 = lane & 15;
  const int nt   = blockIdx.x, mt = blockIdx.y;
  const size_t arow0 = (size_t)mt * 256, brow0 = (size_t)nt * 256;

  f32x4 acc[8][8] = {};

  // staging: load i covers rows i*64 + (tid>>2); src chunk = (tid&3) ^ ((row>>1)&3)
  // (row>>1)&3 == (tid>>3)&3 for all i since i*64 is a multiple of 8.
  const int schk = ((tid & 3) ^ ((tid >> 3) & 3)) * 8;
  const u16* gA = A  + (arow0 + (tid >> 2))*1024 + schk;   // + i*65536 + t*32
  const u16* gB = Bw + (brow0 + (tid >> 2))*1024 + schk;

  // read: fragment rows 16-aligned + c16 -> (row>>1)&3 == (c16>>1)&3
  const int rswz = (g ^ ((c16 >> 1) & 3)) * 8;
  const int abase = (wr*128 + c16)*32 + rswz;          // + m*512 + buf*16384
  const int bbase = 8192 + (wc*128 + c16)*32 + rswz;   // + n*512 + buf*16384

#define GSTAGE(B2) do{ \
    GLD_LDS16(gA,           &lds[(B2)*16384 +         tid*8]); \
    GLD_LDS16(gA +  65536,  &lds[(B2)*16384 +  2048 + tid*8]); \
    GLD_LDS16(gA + 131072,  &lds[(B2)*16384 +  4096 + tid*8]); \
    GLD_LDS16(gA + 196608,  &lds[(B2)*16384 +  6144 + tid*8]); \
    GLD_LDS16(gB,           &lds[(B2)*16384 +  8192 + tid*8]); \
    GLD_LDS16(gB +  65536,  &lds[(B2)*16384 + 10240 + tid*8]); \
    GLD_LDS16(gB + 131072,  &lds[(B2)*16384 + 12288 + tid*8]); \
    GLD_LDS16(gB + 196608,  &lds[(B2)*16384 + 14336 + tid*8]); \
    gA += 32; gB += 32; \
  }while(0)

#define GBODY(B, STG, VMW) do{ \
    if (STG) GSTAGE(((B)+2)%3); \
    bf16x8 af[8], bfr[8]; \
    _Pragma("unroll") \
    for (int m = 0; m < 8; m++) \
      af[m]  = __builtin_bit_cast(bf16x8, *(const uint4*)(&lds[(B)*16384 + abase + m*512])); \
    _Pragma("unroll") \
    for (int n = 0; n < 8; n++) \
      bfr[n] = __builtin_bit_cast(bf16x8, *(const uint4*)(&lds[(B)*16384 + bbase + n*512])); \
    __builtin_amdgcn_s_setprio(1); \
    _Pragma("unroll") \
    for (int m = 0; m < 8; m++) \
      _Pragma("unroll") \
      for (int n = 0; n < 8; n++) \
        acc[m][n] = __builtin_amdgcn_mfma_f32_16x16x32_bf16(af[m], bfr[n], acc[m][n], 0, 0, 0); \
    __builtin_amdgcn_s_setprio(0); \
    if ((VMW) == 8){ asm volatile("s_waitcnt vmcnt(8)" ::: "memory"); __builtin_amdgcn_s_barrier(); } \
    else if ((VMW) == 0){ asm volatile("s_waitcnt vmcnt(0)" ::: "memory"); __builtin_amdgcn_s_barrier(); } \
  }while(0)

  // prologue: tiles 0,1 in flight; retire tile 0 (keep tile 1 = 8 in flight)
  GSTAGE(0); GSTAGE(1);
  asm volatile("s_waitcnt vmcnt(8)" ::: "memory");
  __builtin_amdgcn_s_barrier();

  #pragma unroll 1
  for (int rr = 0; rr < 10; rr++){   // t=0..29; stages t+2 (2..31)
    GBODY(0, 1, 8);
    GBODY(1, 1, 8);
    GBODY(2, 1, 8);
  }
  GBODY(0, 0, 0);    // t=30: drain tile 31
  GBODY(1, 0, -1);   // t=31

#undef GBODY
#undef GSTAGE

  // epilogue: QKV scatter; C/D row=(lane>>4)*4+reg, col=lane&15
  #pragma unroll
  for (int m = 0; m < 8; m++){
    const size_t i0 = arow0 + wr*128 + m*16 + g*4;
    #pragma unroll
    for (int n = 0; n < 8; n++){
      const int o = (int)brow0 + wc*128 + n*16 + c16;
      const float bias_v = bias[o];
      const int proj = o >> 10, wi = o & 1023, hh = wi >> 6, dd = wi & 63;
      if (proj < 2){
        u16* base = (proj == 0) ? q_ws : k_ws;
        const float sc = (proj == 0) ? QSCALE : 1.0f;
        #pragma unroll
        for (int r = 0; r < 4; r++){
          const size_t i = i0 + r;
          const size_t bb = i >> 11, nn = i & 2047;
          base[((bb*16 + hh)*2048 + nn)*64 + dd] = f2bf((acc[m][n][r] + bias_v)*sc);
        }
      } else {
        const size_t bb = i0 >> 11, nn = i0 & 2047;
        union{ u16 u[4]; uint64_t v; } pk;
        #pragma unroll
        for (int r = 0; r < 4; r++) pk.u[r] = f2bf(acc[m][n][r] + bias_v);
        *reinterpret_cast<uint64_t*>(v_ws + ((bb*16 + hh)*64 + dd)*2048 + nn) = pk.v;
      }
    }
  }
}

// ---------------- 128x128 bf16 GEMM, BK=32, 3-ring (output projection) ----------------
__global__ __launch_bounds__(256) void gemm_bt1(
    const u16* __restrict__ A, const u16* __restrict__ Bw,
    const float* __restrict__ bias, float* __restrict__ Cout)
{
  __shared__ u16 lds[3*8192];
  const int tid  = threadIdx.x;
  const int w    = tid >> 6, lane = tid & 63;
  const int wr   = w >> 1,  wc   = w & 1;
  const int g    = lane >> 4, c16 = lane & 15;
  const int nt   = blockIdx.x, mt = blockIdx.y;
  const size_t arow0 = (size_t)mt * 128, brow0 = (size_t)nt * 128;

  f32x4 acc[4][4] = {};

  const int srow  = w*16 + (lane >> 2);
  const int schk  = ((lane & 3) ^ ((lane >> 3) & 3)) * 8;
  const u16* gA = A  + (arow0 + srow)*1024 + schk;
  const u16* gB = Bw + (brow0 + srow)*1024 + schk;

  u16* ldsA0 = &lds[w*512];
  u16* ldsB0 = &lds[4096 + w*512];

  const int rswz = (g ^ ((c16 >> 1) & 3)) * 8;
  const int abase = (wr*64 + c16)*32 + rswz;
  const int bbase = 4096 + (wc*64 + c16)*32 + rswz;

#define GSTAGE(B2) do{ \
    GLD_LDS16(gA,          ldsA0 + (B2)*8192); \
    GLD_LDS16(gA + 65536,  ldsA0 + (B2)*8192 + 2048); \
    GLD_LDS16(gB,          ldsB0 + (B2)*8192); \
    GLD_LDS16(gB + 65536,  ldsB0 + (B2)*8192 + 2048); \
    gA += 32; gB += 32; \
  }while(0)

#define GBODY(B, STG, VMW) do{ \
    if (STG) GSTAGE(((B)+2)%3); \
    bf16x8 af[4], bfr[4]; \
    _Pragma("unroll") \
    for (int m = 0; m < 4; m++) \
      af[m]  = __builtin_bit_cast(bf16x8, *(const uint4*)(&lds[(B)*8192 + abase + m*512])); \
    _Pragma("unroll") \
    for (int n = 0; n < 4; n++) \
      bfr[n] = __builtin_bit_cast(bf16x8, *(const uint4*)(&lds[(B)*8192 + bbase + n*512])); \
    __builtin_amdgcn_s_setprio(1); \
    _Pragma("unroll") \
    for (int m = 0; m < 4; m++) \
      _Pragma("unroll") \
      for (int n = 0; n < 4; n++) \
        acc[m][n] = __builtin_amdgcn_mfma_f32_16x16x32_bf16(af[m], bfr[n], acc[m][n], 0, 0, 0); \
    __builtin_amdgcn_s_setprio(0); \
    if ((VMW) == 4){ asm volatile("s_waitcnt vmcnt(4)" ::: "memory"); __builtin_amdgcn_s_barrier(); } \
    else if ((VMW) == 0){ asm volatile("s_waitcnt vmcnt(0)" ::: "memory"); __builtin_amdgcn_s_barrier(); } \
  }while(0)

  GSTAGE(0); GSTAGE(1);
  asm volatile("s_waitcnt vmcnt(4)" ::: "memory");
  __builtin_amdgcn_s_barrier();

  #pragma unroll 1
  for (int rr = 0; rr < 10; rr++){
    GBODY(0, 1, 4);
    GBODY(1, 1, 4);
    GBODY(2, 1, 4);
  }
  GBODY(0, 0, 0);
  GBODY(1, 0, -1);

#undef GBODY
#undef GSTAGE

  #pragma unroll
  for (int m = 0; m < 4; m++){
    const size_t i0 = arow0 + wr*64 + m*16 + g*4;
    #pragma unroll
    for (int n = 0; n < 4; n++){
      const int o = (int)brow0 + wc*64 + n*16 + c16;
      const float bias_v = bias[o];
      #pragma unroll
      for (int r = 0; r < 4; r++)
        Cout[(i0 + r)*1024 + o] = acc[m][n][r] + bias_v;
    }
  }
}

// ---------------- flash attention (round-16 structure, unchanged) ----------------
__global__ __launch_bounds__(256, 2) void attn_k(
    const u16* __restrict__ Q, const u16* __restrict__ Kb, const u16* __restrict__ Vt,
    u16* __restrict__ O)
{
  __shared__ u16 lds[3*8192];
  const int tid = threadIdx.x, w = tid >> 6, lane = tid & 63;
  const int g = lane >> 4, l16 = lane & 15;

  const int f   = ((blockIdx.x & 7) << 6) | (blockIdx.x >> 3);
  const int qt_ = f & 7, bh = f >> 3;
  const int b = bh >> 4, h = bh & 15;
  const size_t hb = (size_t)bh * 2048 * 64;

  const int qrow0 = qt_*256 + w*64 + l16;
  bf16x8 qf[4][2];
  #pragma unroll
  for (int qt = 0; qt < 4; qt++)
    #pragma unroll
    for (int kc = 0; kc < 2; kc++)
      qf[qt][kc] = __builtin_bit_cast(bf16x8,
        *(const uint4*)(Q + hb + (size_t)(qrow0 + qt*16)*64 + kc*32 + g*8));

  f32x4 acc[4][4] = {};
  f32x4 lacc[4] = {};

  union{ u16 u[8]; bf16x8 f; } one_;
  #pragma unroll
  for (int i = 0; i < 8; i++) one_.u[i] = 0x3F80;
  const bf16x8 onesv = one_.f;

  const int srowL = w*8 + (lane >> 3);
  const int schunk = ((lane & 7) ^ ((lane >> 3) & 7)) * 8;
  const u16* gKs = Kb + hb + (size_t)srowL*64   + schunk;
  const u16* gVs = Vt + hb + (size_t)srowL*2048 + schunk;

  u16* ldsK0 = &lds[w*512];
  u16* ldsV0 = &lds[4096 + w*512];

  const int kb0 = l16*64 + (g ^ (l16 & 7))*8;
  const int kb1 = kb0 ^ 32;
  const int vswz = l16 & 7, vlo = (g & 1)*4, vg2 = g >> 1;
  int vb[2][2];
  #pragma unroll
  for (int p = 0; p < 2; p++)
    #pragma unroll
    for (int pc = 0; pc < 2; pc++)
      vb[p][pc] = l16*64 + (((p*4 + pc*2 + vg2) ^ vswz) << 3) + vlo;

#define STAGE_T(B2) do{ \
    GLD_LDS16(gKs,          ldsK0 + (B2)*8192); \
    GLD_LDS16(gKs + 2048,   ldsK0 + (B2)*8192 + 2048); \
    GLD_LDS16(gVs,          ldsV0 + (B2)*8192); \
    GLD_LDS16(gVs + 65536,  ldsV0 + (B2)*8192 + 2048); \
    gKs += 4096; gVs += 64; \
  }while(0)

#define BODY_T(B, STG, VMW) do{ \
    if (STG) STAGE_T(((B)+2)%3); \
    _Pragma("unroll") \
    for (int p = 0; p < 2; p++){ \
      uint32_t pklo[2][4], pkhi[2][4]; \
      _Pragma("unroll") \
      for (int jh = 0; jh < 2; jh++){ \
        const int jt = p*2 + jh; \
        bf16x8 kf0 = __builtin_bit_cast(bf16x8, *(const uint4*)(&lds[(B)*8192 + jt*1024] + kb0)); \
        bf16x8 kf1 = __builtin_bit_cast(bf16x8, *(const uint4*)(&lds[(B)*8192 + jt*1024] + kb1)); \
        _Pragma("unroll") \
        for (int qt = 0; qt < 4; qt++){ \
          f32x4 st = {0.f,0.f,0.f,0.f}; \
          st = __builtin_amdgcn_mfma_f32_16x16x32_bf16(kf0, qf[qt][0], st, 0, 0, 0); \
          st = __builtin_amdgcn_mfma_f32_16x16x32_bf16(kf1, qf[qt][1], st, 0, 0, 0); \
          const uint32_t y0 = __float_as_uint(fmaf(st[0], 128.f, EXPMAGIC)); \
          const uint32_t y1 = __float_as_uint(fmaf(st[1], 128.f, EXPMAGIC)); \
          const uint32_t y2 = __float_as_uint(fmaf(st[2], 128.f, EXPMAGIC)); \
          const uint32_t y3 = __float_as_uint(fmaf(st[3], 128.f, EXPMAGIC)); \
          pklo[jh][qt] = __builtin_amdgcn_perm(y1, y0, 0x05040100u); \
          pkhi[jh][qt] = __builtin_amdgcn_perm(y3, y2, 0x05040100u); \
        } \
      } \
      union { uint32_t u[4]; bf16x8 f; } pf[4]; \
      _Pragma("unroll") \
      for (int qt = 0; qt < 4; qt++){ \
        pf[qt].u[0] = pklo[0][qt]; pf[qt].u[1] = pkhi[0][qt]; \
        pf[qt].u[2] = pklo[1][qt]; pf[qt].u[3] = pkhi[1][qt]; \
      } \
      __builtin_amdgcn_s_setprio(1); \
      _Pragma("unroll") \
      for (int qt = 0; qt < 4; qt++) \
        lacc[qt] = __builtin_amdgcn_mfma_f32_16x16x32_bf16(onesv, pf[qt].f, lacc[qt], 0, 0, 0); \
      _Pragma("unroll") \
      for (int dt = 0; dt < 4; dt++){ \
        union { uint64_t v[2]; bf16x8 f; } vf; \
        vf.v[0] = *(const uint64_t*)(&lds[(B)*8192 + 4096 + dt*1024] + vb[p][0]); \
        vf.v[1] = *(const uint64_t*)(&lds[(B)*8192 + 4096 + dt*1024] + vb[p][1]); \
        _Pragma("unroll") \
        for (int qt = 0; qt < 4; qt++) \
          acc[dt][qt] = __builtin_amdgcn_mfma_f32_16x16x32_bf16(vf.f, pf[qt].f, acc[dt][qt], 0, 0, 0); \
      } \
      __builtin_amdgcn_s_setprio(0); \
    } \
    if ((VMW) == 4){ asm volatile("s_waitcnt vmcnt(4)" ::: "memory"); __builtin_amdgcn_s_barrier(); } \
    else if ((VMW) == 0){ asm volatile("s_waitcnt vmcnt(0)" ::: "memory"); __builtin_amdgcn_s_barrier(); } \
  }while(0)

  STAGE_T(0); STAGE_T(1);
  asm volatile("s_waitcnt vmcnt(4)" ::: "memory");
  __builtin_amdgcn_s_barrier();

  #pragma unroll 1
  for (int rr = 0; rr < 10; rr++){
    BODY_T(0, 1, 4);
    BODY_T(1, 1, 4);
    BODY_T(2, 1, 4);
  }
  BODY_T(0, 0, 0);
  BODY_T(1, 0, -1);

#undef BODY_T
#undef STAGE_T

  float inv[4];
  #pragma unroll
  for (int qt = 0; qt < 4; qt++) inv[qt] = 1.f / lacc[qt][0];

  #pragma unroll
  for (int qt = 0; qt < 4; qt++){
    const size_t ob = (((size_t)(b*2048 + qrow0 + qt*16))*16 + h)*64;
    #pragma unroll
    for (int dt = 0; dt < 4; dt++){
      union{ u16 u[4]; uint64_t v; } pkk;
      #pragma unroll
      for (int r = 0; r < 4; r++) pkk.u[r] = f2bf(acc[dt][qt][r] * inv[qt]);
      *reinterpret_cast<uint64_t*>(O + ob + dt*16 + g*4) = pkk.v;
    }
  }
}

// ---------------- launch ----------------
extern "C" void kernel_launch(void* const* d_in, const int* in_sizes, int n_in,
                              void* d_out, int out_size, void* d_ws, size_t ws_size,
                              hipStream_t stream)
{
  const float* x  = (const float*)d_in[0];
  const float* Wq = (const float*)d_in[1];
  const float* bq = (const float*)d_in[2];
  const float* Wk = (const float*)d_in[3];
  const float* bk = (const float*)d_in[4];
  const float* Wv = (const float*)d_in[5];
  const float* bv = (const float*)d_in[6];
  const float* Wo = (const float*)d_in[7];
  const float* bo = (const float*)d_in[8];
  float* out = (float*)d_out;

  char* ws = (char*)d_ws;
  size_t off = 0;
  auto bump = [&](size_t bytes){ size_t o = off; off = (off + bytes + 255) & ~(size_t)255; return o; };
  u16*  xb   = (u16*)  (ws + bump(8388608ull*2));
  u16*  wqkv = (u16*)  (ws + bump(3145728ull*2));
  u16*  wob  = (u16*)  (ws + bump(1048576ull*2));
  float* bqkv= (float*)(ws + bump(3072ull*4));
  u16*  qws  = (u16*)  (ws + bump(8388608ull*2));
  u16*  kws  = (u16*)  (ws + bump(8388608ull*2));
  u16*  vws  = (u16*)  (ws + bump(8388608ull*2));
  u16*  att  = (u16*)  (ws + bump(8388608ull*2));

  k_prep<<<2048, 256, 0, stream>>>(
      (const float4*)x, (const float4*)Wq, (const float4*)Wk, (const float4*)Wv, (const float4*)Wo,
      (const float4*)bq, (const float4*)bk, (const float4*)bv,
      (uint64_t*)xb, (uint64_t*)wqkv, (uint64_t*)wob, (float4*)bqkv);

  gemm256w<<<dim3(12, 32), 256, 0, stream>>>(xb, wqkv, bqkv, qws, kws, vws);
  attn_k<<<512, 256, 0, stream>>>(qws, kws, vws, att);
  gemm_bt1<<<dim3(8, 64), 256, 0, stream>>>(att, wob, bo, out);
}

// Round 18
// 156.935 us; speedup vs baseline: 1.0988x; 1.0988x over previous
//
#include <hip/hip_runtime.h>
#include <stdint.h>

typedef unsigned short u16;
typedef __bf16 bf16x8 __attribute__((ext_vector_type(8)));
typedef float f32x4 __attribute__((ext_vector_type(4)));

#define QSCALE (19.5f/1024.0f * 1.44269504088896340736f)
// float-magic Schraudolph: y = fma(s,128, 2^23*1.5 + 16250) -> low16(bits(y)) = bf16bits(exp2(s))
#define EXPMAGIC 12599162.0f

__device__ __forceinline__ u16 f2bf(float f){
  uint32_t u = __float_as_uint(f);
  return (u16)((u + 0x7FFFu + ((u >> 16) & 1u)) >> 16);   // RNE
}

__device__ __forceinline__ uint64_t cvt4(float4 f){
  union{ u16 u[4]; uint64_t v; } pk;
  pk.u[0]=f2bf(f.x); pk.u[1]=f2bf(f.y); pk.u[2]=f2bf(f.z); pk.u[3]=f2bf(f.w);
  return pk.v;
}

#define GLD_LDS16(g,l) __builtin_amdgcn_global_load_lds( \
    (const __attribute__((address_space(1))) void*)(g),  \
    (__attribute__((address_space(3))) void*)(l), 16, 0, 0)

// ---------------- fused prep ----------------
__global__ __launch_bounds__(256) void k_prep(
    const float4* __restrict__ x,  const float4* __restrict__ Wq,
    const float4* __restrict__ Wk, const float4* __restrict__ Wv,
    const float4* __restrict__ Wo,
    const float4* __restrict__ bq, const float4* __restrict__ bk, const float4* __restrict__ bv,
    uint64_t* __restrict__ xb, uint64_t* __restrict__ wqkv, uint64_t* __restrict__ wob,
    float4* __restrict__ bqkv)
{
  const int NX = 2097152, NW = 262144;
  const int total = NX + 4*NW + 768;
  int i = blockIdx.x*256 + threadIdx.x;
  const int stride = gridDim.x*256;
  for (; i < total; i += stride){
    if (i < NX)             xb[i] = cvt4(x[i]);
    else if (i < NX+NW)     { int j = i-NX;      wqkv[j]      = cvt4(Wq[j]); }
    else if (i < NX+2*NW)   { int j = i-NX-NW;   wqkv[NW+j]   = cvt4(Wk[j]); }
    else if (i < NX+3*NW)   { int j = i-NX-2*NW; wqkv[2*NW+j] = cvt4(Wv[j]); }
    else if (i < NX+4*NW)   { int j = i-NX-3*NW; wob[j]       = cvt4(Wo[j]); }
    else {
      int j = i - NX - 4*NW;
      bqkv[j] = (j < 256) ? bq[j] : (j < 512 ? bk[j-256] : bv[j-512]);
    }
  }
}

// ---------------- 128x256 bf16 GEMM (QKV proj): 8 waves (2Mx4N), wave-tile 64x64 ----------------
// BK=32, 3-ring (72KB -> 2 blocks/CU = 4 waves/SIMD), stage-2-ahead, counted vmcnt(3).
// Per-wave geometry identical to proven 128^2 kernel (8 b128 : 16 MFMA).
// Grid 12x64 = 768 = exactly 3 rounds of 256 CUs.
// Balanced swizzle: LDS[row][c] = global[row][c ^ ((row>>1)&3)].
__global__ __launch_bounds__(512) void gemm128x256(
    const u16* __restrict__ A, const u16* __restrict__ Bw,
    const float* __restrict__ bias,
    u16* __restrict__ q_ws, u16* __restrict__ k_ws, u16* __restrict__ v_ws)
{
  __shared__ u16 lds[3*12288];   // [buf:3][ A:128x32 (4096 u16) | B:256x32 (8192 u16) ]
  const int tid  = threadIdx.x;
  const int w    = tid >> 6, lane = tid & 63;
  const int wr   = w >> 2,  wc   = w & 3;       // 2 M-halves x 4 N-quads
  const int g    = lane >> 4, c16 = lane & 15;
  const int nt   = blockIdx.x, mt = blockIdx.y;
  const size_t arow0 = (size_t)mt * 128, brow0 = (size_t)nt * 256;

  f32x4 acc[4][4] = {};

  // staging: thread covers row tid>>2, chunk (tid&3)^((row>>1)&3); (row>>1)&3 == (tid>>3)&3
  const int schk = ((tid & 3) ^ ((tid >> 3) & 3)) * 8;
  const u16* gA = A  + (arow0 + (tid >> 2))*1024 + schk;   // + t*32
  const u16* gB = Bw + (brow0 + (tid >> 2))*1024 + schk;   // + L*131072 + t*32

  // read: fragment rows 16-aligned + c16 -> (row>>1)&3 == (c16>>1)&3
  const int rswz = (g ^ ((c16 >> 1) & 3)) * 8;
  const int abase = (wr*64 + c16)*32 + rswz;          // + m*512 + buf*12288
  const int bbase = 4096 + (wc*64 + c16)*32 + rswz;   // + n*512 + buf*12288

#define GSTAGE(B2) do{ \
    GLD_LDS16(gA,           &lds[(B2)*12288 +        tid*8]); \
    GLD_LDS16(gB,           &lds[(B2)*12288 + 4096 + tid*8]); \
    GLD_LDS16(gB + 131072,  &lds[(B2)*12288 + 8192 + tid*8]); \
    gA += 32; gB += 32; \
  }while(0)

#define GBODY(B, STG, VMW) do{ \
    if (STG) GSTAGE(((B)+2)%3); \
    bf16x8 af[4], bfr[4]; \
    _Pragma("unroll") \
    for (int m = 0; m < 4; m++) \
      af[m]  = __builtin_bit_cast(bf16x8, *(const uint4*)(&lds[(B)*12288 + abase + m*512])); \
    _Pragma("unroll") \
    for (int n = 0; n < 4; n++) \
      bfr[n] = __builtin_bit_cast(bf16x8, *(const uint4*)(&lds[(B)*12288 + bbase + n*512])); \
    __builtin_amdgcn_s_setprio(1); \
    _Pragma("unroll") \
    for (int m = 0; m < 4; m++) \
      _Pragma("unroll") \
      for (int n = 0; n < 4; n++) \
        acc[m][n] = __builtin_amdgcn_mfma_f32_16x16x32_bf16(af[m], bfr[n], acc[m][n], 0, 0, 0); \
    __builtin_amdgcn_s_setprio(0); \
    if ((VMW) == 3){ asm volatile("s_waitcnt vmcnt(3)" ::: "memory"); __builtin_amdgcn_s_barrier(); } \
    else if ((VMW) == 0){ asm volatile("s_waitcnt vmcnt(0)" ::: "memory"); __builtin_amdgcn_s_barrier(); } \
  }while(0)

  // prologue: tiles 0,1 in flight (6 loads); retire tile 0's 3, keep tile 1's 3
  GSTAGE(0); GSTAGE(1);
  asm volatile("s_waitcnt vmcnt(3)" ::: "memory");
  __builtin_amdgcn_s_barrier();

  #pragma unroll 1
  for (int rr = 0; rr < 10; rr++){   // t=0..29; stages t+2 (2..31)
    GBODY(0, 1, 3);
    GBODY(1, 1, 3);
    GBODY(2, 1, 3);
  }
  GBODY(0, 0, 0);    // t=30: drain tile 31
  GBODY(1, 0, -1);   // t=31

#undef GBODY
#undef GSTAGE

  // epilogue: QKV scatter; C/D row=(lane>>4)*4+reg, col=lane&15
  #pragma unroll
  for (int m = 0; m < 4; m++){
    const size_t i0 = arow0 + wr*64 + m*16 + g*4;
    #pragma unroll
    for (int n = 0; n < 4; n++){
      const int o = (int)brow0 + wc*64 + n*16 + c16;
      const float bias_v = bias[o];
      const int proj = o >> 10, wi = o & 1023, hh = wi >> 6, dd = wi & 63;
      if (proj < 2){
        u16* base = (proj == 0) ? q_ws : k_ws;
        const float sc = (proj == 0) ? QSCALE : 1.0f;
        #pragma unroll
        for (int r = 0; r < 4; r++){
          const size_t i = i0 + r;
          const size_t bb = i >> 11, nn = i & 2047;
          base[((bb*16 + hh)*2048 + nn)*64 + dd] = f2bf((acc[m][n][r] + bias_v)*sc);
        }
      } else {
        const size_t bb = i0 >> 11, nn = i0 & 2047;
        union{ u16 u[4]; uint64_t v; } pk;
        #pragma unroll
        for (int r = 0; r < 4; r++) pk.u[r] = f2bf(acc[m][n][r] + bias_v);
        *reinterpret_cast<uint64_t*>(v_ws + ((bb*16 + hh)*64 + dd)*2048 + nn) = pk.v;
      }
    }
  }
}

// ---------------- 128x128 bf16 GEMM, BK=32, 3-ring (output projection) ----------------
__global__ __launch_bounds__(256) void gemm_bt1(
    const u16* __restrict__ A, const u16* __restrict__ Bw,
    const float* __restrict__ bias, float* __restrict__ Cout)
{
  __shared__ u16 lds[3*8192];
  const int tid  = threadIdx.x;
  const int w    = tid >> 6, lane = tid & 63;
  const int wr   = w >> 1,  wc   = w & 1;
  const int g    = lane >> 4, c16 = lane & 15;
  const int nt   = blockIdx.x, mt = blockIdx.y;
  const size_t arow0 = (size_t)mt * 128, brow0 = (size_t)nt * 128;

  f32x4 acc[4][4] = {};

  const int srow  = w*16 + (lane >> 2);
  const int schk  = ((lane & 3) ^ ((lane >> 3) & 3)) * 8;
  const u16* gA = A  + (arow0 + srow)*1024 + schk;
  const u16* gB = Bw + (brow0 + srow)*1024 + schk;

  u16* ldsA0 = &lds[w*512];
  u16* ldsB0 = &lds[4096 + w*512];

  const int rswz = (g ^ ((c16 >> 1) & 3)) * 8;
  const int abase = (wr*64 + c16)*32 + rswz;
  const int bbase = 4096 + (wc*64 + c16)*32 + rswz;

#define GSTAGE(B2) do{ \
    GLD_LDS16(gA,          ldsA0 + (B2)*8192); \
    GLD_LDS16(gA + 65536,  ldsA0 + (B2)*8192 + 2048); \
    GLD_LDS16(gB,          ldsB0 + (B2)*8192); \
    GLD_LDS16(gB + 65536,  ldsB0 + (B2)*8192 + 2048); \
    gA += 32; gB += 32; \
  }while(0)

#define GBODY(B, STG, VMW) do{ \
    if (STG) GSTAGE(((B)+2)%3); \
    bf16x8 af[4], bfr[4]; \
    _Pragma("unroll") \
    for (int m = 0; m < 4; m++) \
      af[m]  = __builtin_bit_cast(bf16x8, *(const uint4*)(&lds[(B)*8192 + abase + m*512])); \
    _Pragma("unroll") \
    for (int n = 0; n < 4; n++) \
      bfr[n] = __builtin_bit_cast(bf16x8, *(const uint4*)(&lds[(B)*8192 + bbase + n*512])); \
    __builtin_amdgcn_s_setprio(1); \
    _Pragma("unroll") \
    for (int m = 0; m < 4; m++) \
      _Pragma("unroll") \
      for (int n = 0; n < 4; n++) \
        acc[m][n] = __builtin_amdgcn_mfma_f32_16x16x32_bf16(af[m], bfr[n], acc[m][n], 0, 0, 0); \
    __builtin_amdgcn_s_setprio(0); \
    if ((VMW) == 4){ asm volatile("s_waitcnt vmcnt(4)" ::: "memory"); __builtin_amdgcn_s_barrier(); } \
    else if ((VMW) == 0){ asm volatile("s_waitcnt vmcnt(0)" ::: "memory"); __builtin_amdgcn_s_barrier(); } \
  }while(0)

  GSTAGE(0); GSTAGE(1);
  asm volatile("s_waitcnt vmcnt(4)" ::: "memory");
  __builtin_amdgcn_s_barrier();

  #pragma unroll 1
  for (int rr = 0; rr < 10; rr++){
    GBODY(0, 1, 4);
    GBODY(1, 1, 4);
    GBODY(2, 1, 4);
  }
  GBODY(0, 0, 0);
  GBODY(1, 0, -1);

#undef GBODY
#undef GSTAGE

  #pragma unroll
  for (int m = 0; m < 4; m++){
    const size_t i0 = arow0 + wr*64 + m*16 + g*4;
    #pragma unroll
    for (int n = 0; n < 4; n++){
      const int o = (int)brow0 + wc*64 + n*16 + c16;
      const float bias_v = bias[o];
      #pragma unroll
      for (int r = 0; r < 4; r++)
        Cout[(i0 + r)*1024 + o] = acc[m][n][r] + bias_v;
    }
  }
}

// ---------------- flash attention (round-16 structure, unchanged) ----------------
__global__ __launch_bounds__(256, 2) void attn_k(
    const u16* __restrict__ Q, const u16* __restrict__ Kb, const u16* __restrict__ Vt,
    u16* __restrict__ O)
{
  __shared__ u16 lds[3*8192];
  const int tid = threadIdx.x, w = tid >> 6, lane = tid & 63;
  const int g = lane >> 4, l16 = lane & 15;

  const int f   = ((blockIdx.x & 7) << 6) | (blockIdx.x >> 3);
  const int qt_ = f & 7, bh = f >> 3;
  const int b = bh >> 4, h = bh & 15;
  const size_t hb = (size_t)bh * 2048 * 64;

  const int qrow0 = qt_*256 + w*64 + l16;
  bf16x8 qf[4][2];
  #pragma unroll
  for (int qt = 0; qt < 4; qt++)
    #pragma unroll
    for (int kc = 0; kc < 2; kc++)
      qf[qt][kc] = __builtin_bit_cast(bf16x8,
        *(const uint4*)(Q + hb + (size_t)(qrow0 + qt*16)*64 + kc*32 + g*8));

  f32x4 acc[4][4] = {};
  f32x4 lacc[4] = {};

  union{ u16 u[8]; bf16x8 f; } one_;
  #pragma unroll
  for (int i = 0; i < 8; i++) one_.u[i] = 0x3F80;
  const bf16x8 onesv = one_.f;

  const int srowL = w*8 + (lane >> 3);
  const int schunk = ((lane & 7) ^ ((lane >> 3) & 7)) * 8;
  const u16* gKs = Kb + hb + (size_t)srowL*64   + schunk;
  const u16* gVs = Vt + hb + (size_t)srowL*2048 + schunk;

  u16* ldsK0 = &lds[w*512];
  u16* ldsV0 = &lds[4096 + w*512];

  const int kb0 = l16*64 + (g ^ (l16 & 7))*8;
  const int kb1 = kb0 ^ 32;
  const int vswz = l16 & 7, vlo = (g & 1)*4, vg2 = g >> 1;
  int vb[2][2];
  #pragma unroll
  for (int p = 0; p < 2; p++)
    #pragma unroll
    for (int pc = 0; pc < 2; pc++)
      vb[p][pc] = l16*64 + (((p*4 + pc*2 + vg2) ^ vswz) << 3) + vlo;

#define STAGE_T(B2) do{ \
    GLD_LDS16(gKs,          ldsK0 + (B2)*8192); \
    GLD_LDS16(gKs + 2048,   ldsK0 + (B2)*8192 + 2048); \
    GLD_LDS16(gVs,          ldsV0 + (B2)*8192); \
    GLD_LDS16(gVs + 65536,  ldsV0 + (B2)*8192 + 2048); \
    gKs += 4096; gVs += 64; \
  }while(0)

#define BODY_T(B, STG, VMW) do{ \
    if (STG) STAGE_T(((B)+2)%3); \
    _Pragma("unroll") \
    for (int p = 0; p < 2; p++){ \
      uint32_t pklo[2][4], pkhi[2][4]; \
      _Pragma("unroll") \
      for (int jh = 0; jh < 2; jh++){ \
        const int jt = p*2 + jh; \
        bf16x8 kf0 = __builtin_bit_cast(bf16x8, *(const uint4*)(&lds[(B)*8192 + jt*1024] + kb0)); \
        bf16x8 kf1 = __builtin_bit_cast(bf16x8, *(const uint4*)(&lds[(B)*8192 + jt*1024] + kb1)); \
        _Pragma("unroll") \
        for (int qt = 0; qt < 4; qt++){ \
          f32x4 st = {0.f,0.f,0.f,0.f}; \
          st = __builtin_amdgcn_mfma_f32_16x16x32_bf16(kf0, qf[qt][0], st, 0, 0, 0); \
          st = __builtin_amdgcn_mfma_f32_16x16x32_bf16(kf1, qf[qt][1], st, 0, 0, 0); \
          const uint32_t y0 = __float_as_uint(fmaf(st[0], 128.f, EXPMAGIC)); \
          const uint32_t y1 = __float_as_uint(fmaf(st[1], 128.f, EXPMAGIC)); \
          const uint32_t y2 = __float_as_uint(fmaf(st[2], 128.f, EXPMAGIC)); \
          const uint32_t y3 = __float_as_uint(fmaf(st[3], 128.f, EXPMAGIC)); \
          pklo[jh][qt] = __builtin_amdgcn_perm(y1, y0, 0x05040100u); \
          pkhi[jh][qt] = __builtin_amdgcn_perm(y3, y2, 0x05040100u); \
        } \
      } \
      union { uint32_t u[4]; bf16x8 f; } pf[4]; \
      _Pragma("unroll") \
      for (int qt = 0; qt < 4; qt++){ \
        pf[qt].u[0] = pklo[0][qt]; pf[qt].u[1] = pkhi[0][qt]; \
        pf[qt].u[2] = pklo[1][qt]; pf[qt].u[3] = pkhi[1][qt]; \
      } \
      __builtin_amdgcn_s_setprio(1); \
      _Pragma("unroll") \
      for (int qt = 0; qt < 4; qt++) \
        lacc[qt] = __builtin_amdgcn_mfma_f32_16x16x32_bf16(onesv, pf[qt].f, lacc[qt], 0, 0, 0); \
      _Pragma("unroll") \
      for (int dt = 0; dt < 4; dt++){ \
        union { uint64_t v[2]; bf16x8 f; } vf; \
        vf.v[0] = *(const uint64_t*)(&lds[(B)*8192 + 4096 + dt*1024] + vb[p][0]); \
        vf.v[1] = *(const uint64_t*)(&lds[(B)*8192 + 4096 + dt*1024] + vb[p][1]); \
        _Pragma("unroll") \
        for (int qt = 0; qt < 4; qt++) \
          acc[dt][qt] = __builtin_amdgcn_mfma_f32_16x16x32_bf16(vf.f, pf[qt].f, acc[dt][qt], 0, 0, 0); \
      } \
      __builtin_amdgcn_s_setprio(0); \
    } \
    if ((VMW) == 4){ asm volatile("s_waitcnt vmcnt(4)" ::: "memory"); __builtin_amdgcn_s_barrier(); } \
    else if ((VMW) == 0){ asm volatile("s_waitcnt vmcnt(0)" ::: "memory"); __builtin_amdgcn_s_barrier(); } \
  }while(0)

  STAGE_T(0); STAGE_T(1);
  asm volatile("s_waitcnt vmcnt(4)" ::: "memory");
  __builtin_amdgcn_s_barrier();

  #pragma unroll 1
  for (int rr = 0; rr < 10; rr++){
    BODY_T(0, 1, 4);
    BODY_T(1, 1, 4);
    BODY_T(2, 1, 4);
  }
  BODY_T(0, 0, 0);
  BODY_T(1, 0, -1);

#undef BODY_T
#undef STAGE_T

  float inv[4];
  #pragma unroll
  for (int qt = 0; qt < 4; qt++) inv[qt] = 1.f / lacc[qt][0];

  #pragma unroll
  for (int qt = 0; qt < 4; qt++){
    const size_t ob = (((size_t)(b*2048 + qrow0 + qt*16))*16 + h)*64;
    #pragma unroll
    for (int dt = 0; dt < 4; dt++){
      union{ u16 u[4]; uint64_t v; } pkk;
      #pragma unroll
      for (int r = 0; r < 4; r++) pkk.u[r] = f2bf(acc[dt][qt][r] * inv[qt]);
      *reinterpret_cast<uint64_t*>(O + ob + dt*16 + g*4) = pkk.v;
    }
  }
}

// ---------------- launch ----------------
extern "C" void kernel_launch(void* const* d_in, const int* in_sizes, int n_in,
                              void* d_out, int out_size, void* d_ws, size_t ws_size,
                              hipStream_t stream)
{
  const float* x  = (const float*)d_in[0];
  const float* Wq = (const float*)d_in[1];
  const float* bq = (const float*)d_in[2];
  const float* Wk = (const float*)d_in[3];
  const float* bk = (const float*)d_in[4];
  const float* Wv = (const float*)d_in[5];
  const float* bv = (const float*)d_in[6];
  const float* Wo = (const float*)d_in[7];
  const float* bo = (const float*)d_in[8];
  float* out = (float*)d_out;

  char* ws = (char*)d_ws;
  size_t off = 0;
  auto bump = [&](size_t bytes){ size_t o = off; off = (off + bytes + 255) & ~(size_t)255; return o; };
  u16*  xb   = (u16*)  (ws + bump(8388608ull*2));
  u16*  wqkv = (u16*)  (ws + bump(3145728ull*2));
  u16*  wob  = (u16*)  (ws + bump(1048576ull*2));
  float* bqkv= (float*)(ws + bump(3072ull*4));
  u16*  qws  = (u16*)  (ws + bump(8388608ull*2));
  u16*  kws  = (u16*)  (ws + bump(8388608ull*2));
  u16*  vws  = (u16*)  (ws + bump(8388608ull*2));
  u16*  att  = (u16*)  (ws + bump(8388608ull*2));

  k_prep<<<2048, 256, 0, stream>>>(
      (const float4*)x, (const float4*)Wq, (const float4*)Wk, (const float4*)Wv, (const float4*)Wo,
      (const float4*)bq, (const float4*)bk, (const float4*)bv,
      (uint64_t*)xb, (uint64_t*)wqkv, (uint64_t*)wob, (float4*)bqkv);

  gemm128x256<<<dim3(12, 64), 512, 0, stream>>>(xb, wqkv, bqkv, qws, kws, vws);
  attn_k<<<512, 256, 0, stream>>>(qws, kws, vws, att);
  gemm_bt1<<<dim3(8, 64), 256, 0, stream>>>(att, wob, bo, out);
}

// Round 19
// 156.064 us; speedup vs baseline: 1.1049x; 1.0056x over previous
//
#include <hip/hip_runtime.h>
#include <stdint.h>

typedef unsigned short u16;
typedef __bf16 bf16x8 __attribute__((ext_vector_type(8)));
typedef float f32x4 __attribute__((ext_vector_type(4)));

#define QSCALE (19.5f/1024.0f * 1.44269504088896340736f)
// float-magic Schraudolph: y = fma(s,128, 2^23*1.5 + 16250) -> low16(bits(y)) = bf16bits(exp2(s))
#define EXPMAGIC 12599162.0f

__device__ __forceinline__ u16 f2bf(float f){
  uint32_t u = __float_as_uint(f);
  return (u16)((u + 0x7FFFu + ((u >> 16) & 1u)) >> 16);   // RNE
}

__device__ __forceinline__ uint64_t cvt4(float4 f){
  union{ u16 u[4]; uint64_t v; } pk;
  pk.u[0]=f2bf(f.x); pk.u[1]=f2bf(f.y); pk.u[2]=f2bf(f.z); pk.u[3]=f2bf(f.w);
  return pk.v;
}

#define GLD_LDS16(g,l) __builtin_amdgcn_global_load_lds( \
    (const __attribute__((address_space(1))) void*)(g),  \
    (__attribute__((address_space(3))) void*)(l), 16, 0, 0)

// ---------------- fused prep ----------------
__global__ __launch_bounds__(256) void k_prep(
    const float4* __restrict__ x,  const float4* __restrict__ Wq,
    const float4* __restrict__ Wk, const float4* __restrict__ Wv,
    const float4* __restrict__ Wo,
    const float4* __restrict__ bq, const float4* __restrict__ bk, const float4* __restrict__ bv,
    uint64_t* __restrict__ xb, uint64_t* __restrict__ wqkv, uint64_t* __restrict__ wob,
    float4* __restrict__ bqkv)
{
  const int NX = 2097152, NW = 262144;
  const int total = NX + 4*NW + 768;
  int i = blockIdx.x*256 + threadIdx.x;
  const int stride = gridDim.x*256;
  for (; i < total; i += stride){
    if (i < NX)             xb[i] = cvt4(x[i]);
    else if (i < NX+NW)     { int j = i-NX;      wqkv[j]      = cvt4(Wq[j]); }
    else if (i < NX+2*NW)   { int j = i-NX-NW;   wqkv[NW+j]   = cvt4(Wk[j]); }
    else if (i < NX+3*NW)   { int j = i-NX-2*NW; wqkv[2*NW+j] = cvt4(Wv[j]); }
    else if (i < NX+4*NW)   { int j = i-NX-3*NW; wob[j]       = cvt4(Wo[j]); }
    else {
      int j = i - NX - 4*NW;
      bqkv[j] = (j < 256) ? bq[j] : (j < 512 ? bk[j-256] : bv[j-512]);
    }
  }
}

// ---------------- 128x256 bf16 GEMM: 8 waves (2Mx4N), wave-tile 64x64 ----------------
// BK=32, 3-ring (72KB -> 2 blocks/CU), stage-2-ahead, counted vmcnt(3).
// MODE 0: QKV projection (grid 12x64); MODE 1: output projection -> fp32 (grid 4x64).
// Balanced swizzle: LDS[row][c] = global[row][c ^ ((row>>1)&3)].
template<int MODE>
__global__ __launch_bounds__(512) void gemm128x256(
    const u16* __restrict__ A, const u16* __restrict__ Bw,
    const float* __restrict__ bias, float* __restrict__ Cout,
    u16* __restrict__ q_ws, u16* __restrict__ k_ws, u16* __restrict__ v_ws)
{
  __shared__ u16 lds[3*12288];   // [buf:3][ A:128x32 (4096 u16) | B:256x32 (8192 u16) ]
  const int tid  = threadIdx.x;
  const int w    = tid >> 6, lane = tid & 63;
  const int wr   = w >> 2,  wc   = w & 3;
  const int g    = lane >> 4, c16 = lane & 15;
  const int nt   = blockIdx.x, mt = blockIdx.y;
  const size_t arow0 = (size_t)mt * 128, brow0 = (size_t)nt * 256;

  f32x4 acc[4][4] = {};

  const int schk = ((tid & 3) ^ ((tid >> 3) & 3)) * 8;
  const u16* gA = A  + (arow0 + (tid >> 2))*1024 + schk;
  const u16* gB = Bw + (brow0 + (tid >> 2))*1024 + schk;

  const int rswz = (g ^ ((c16 >> 1) & 3)) * 8;
  const int abase = (wr*64 + c16)*32 + rswz;
  const int bbase = 4096 + (wc*64 + c16)*32 + rswz;

#define GSTAGE(B2) do{ \
    GLD_LDS16(gA,           &lds[(B2)*12288 +        tid*8]); \
    GLD_LDS16(gB,           &lds[(B2)*12288 + 4096 + tid*8]); \
    GLD_LDS16(gB + 131072,  &lds[(B2)*12288 + 8192 + tid*8]); \
    gA += 32; gB += 32; \
  }while(0)

#define GBODY(B, STG, VMW) do{ \
    if (STG) GSTAGE(((B)+2)%3); \
    bf16x8 af[4], bfr[4]; \
    _Pragma("unroll") \
    for (int m = 0; m < 4; m++) \
      af[m]  = __builtin_bit_cast(bf16x8, *(const uint4*)(&lds[(B)*12288 + abase + m*512])); \
    _Pragma("unroll") \
    for (int n = 0; n < 4; n++) \
      bfr[n] = __builtin_bit_cast(bf16x8, *(const uint4*)(&lds[(B)*12288 + bbase + n*512])); \
    __builtin_amdgcn_s_setprio(1); \
    _Pragma("unroll") \
    for (int m = 0; m < 4; m++) \
      _Pragma("unroll") \
      for (int n = 0; n < 4; n++) \
        acc[m][n] = __builtin_amdgcn_mfma_f32_16x16x32_bf16(af[m], bfr[n], acc[m][n], 0, 0, 0); \
    __builtin_amdgcn_s_setprio(0); \
    if ((VMW) == 3){ asm volatile("s_waitcnt vmcnt(3)" ::: "memory"); __builtin_amdgcn_s_barrier(); } \
    else if ((VMW) == 0){ asm volatile("s_waitcnt vmcnt(0)" ::: "memory"); __builtin_amdgcn_s_barrier(); } \
  }while(0)

  GSTAGE(0); GSTAGE(1);
  asm volatile("s_waitcnt vmcnt(3)" ::: "memory");
  __builtin_amdgcn_s_barrier();

  #pragma unroll 1
  for (int rr = 0; rr < 10; rr++){
    GBODY(0, 1, 3);
    GBODY(1, 1, 3);
    GBODY(2, 1, 3);
  }
  GBODY(0, 0, 0);
  GBODY(1, 0, -1);

#undef GBODY
#undef GSTAGE

  #pragma unroll
  for (int m = 0; m < 4; m++){
    const size_t i0 = arow0 + wr*64 + m*16 + g*4;
    #pragma unroll
    for (int n = 0; n < 4; n++){
      const int o = (int)brow0 + wc*64 + n*16 + c16;
      const float bias_v = bias[o];
      if (MODE == 0){
        const int proj = o >> 10, wi = o & 1023, hh = wi >> 6, dd = wi & 63;
        if (proj < 2){
          u16* base = (proj == 0) ? q_ws : k_ws;
          const float sc = (proj == 0) ? QSCALE : 1.0f;
          #pragma unroll
          for (int r = 0; r < 4; r++){
            const size_t i = i0 + r;
            const size_t bb = i >> 11, nn = i & 2047;
            base[((bb*16 + hh)*2048 + nn)*64 + dd] = f2bf((acc[m][n][r] + bias_v)*sc);
          }
        } else {
          const size_t bb = i0 >> 11, nn = i0 & 2047;
          union{ u16 u[4]; uint64_t v; } pk;
          #pragma unroll
          for (int r = 0; r < 4; r++) pk.u[r] = f2bf(acc[m][n][r] + bias_v);
          *reinterpret_cast<uint64_t*>(v_ws + ((bb*16 + hh)*64 + dd)*2048 + nn) = pk.v;
        }
      } else {
        #pragma unroll
        for (int r = 0; r < 4; r++)
          Cout[(i0 + r)*1024 + o] = acc[m][n][r] + bias_v;
      }
    }
  }
}

// ---------------- flash attention: 4-ring, paired tiles, barrier every 2 tiles ----------------
__global__ __launch_bounds__(256, 2) void attn_k(
    const u16* __restrict__ Q, const u16* __restrict__ Kb, const u16* __restrict__ Vt,
    u16* __restrict__ O)
{
  __shared__ u16 lds[4*8192];   // [buf:4][ K:4096 | V:4096 ], XOR-8 swizzled 16B slots
  const int tid = threadIdx.x, w = tid >> 6, lane = tid & 63;
  const int g = lane >> 4, l16 = lane & 15;

  const int f   = ((blockIdx.x & 7) << 6) | (blockIdx.x >> 3);
  const int qt_ = f & 7, bh = f >> 3;
  const int b = bh >> 4, h = bh & 15;
  const size_t hb = (size_t)bh * 2048 * 64;

  const int qrow0 = qt_*256 + w*64 + l16;
  bf16x8 qf[4][2];
  #pragma unroll
  for (int qt = 0; qt < 4; qt++)
    #pragma unroll
    for (int kc = 0; kc < 2; kc++)
      qf[qt][kc] = __builtin_bit_cast(bf16x8,
        *(const uint4*)(Q + hb + (size_t)(qrow0 + qt*16)*64 + kc*32 + g*8));

  f32x4 acc[4][4] = {};
  f32x4 lacc[4] = {};

  union{ u16 u[8]; bf16x8 f; } one_;
  #pragma unroll
  for (int i = 0; i < 8; i++) one_.u[i] = 0x3F80;
  const bf16x8 onesv = one_.f;

  const int srowL = w*8 + (lane >> 3);
  const int schunk = ((lane & 7) ^ ((lane >> 3) & 7)) * 8;
  const u16* gKs = Kb + hb + (size_t)srowL*64   + schunk;
  const u16* gVs = Vt + hb + (size_t)srowL*2048 + schunk;

  u16* ldsK0 = &lds[w*512];
  u16* ldsV0 = &lds[4096 + w*512];

  const int kb0 = l16*64 + (g ^ (l16 & 7))*8;
  const int kb1 = kb0 ^ 32;
  const int vswz = l16 & 7, vlo = (g & 1)*4, vg2 = g >> 1;
  int vb[2][2];
  #pragma unroll
  for (int p = 0; p < 2; p++)
    #pragma unroll
    for (int pc = 0; pc < 2; pc++)
      vb[p][pc] = l16*64 + (((p*4 + pc*2 + vg2) ^ vswz) << 3) + vlo;

#define STAGE_T(B2) do{ \
    GLD_LDS16(gKs,          ldsK0 + (B2)*8192); \
    GLD_LDS16(gKs + 2048,   ldsK0 + (B2)*8192 + 2048); \
    GLD_LDS16(gVs,          ldsV0 + (B2)*8192); \
    GLD_LDS16(gVs + 65536,  ldsV0 + (B2)*8192 + 2048); \
    gKs += 4096; gVs += 64; \
  }while(0)

// one j-tile of compute on buffer B (no stage, no sync)
#define TILE_T(B) do{ \
    _Pragma("unroll") \
    for (int p = 0; p < 2; p++){ \
      uint32_t pklo[2][4], pkhi[2][4]; \
      _Pragma("unroll") \
      for (int jh = 0; jh < 2; jh++){ \
        const int jt = p*2 + jh; \
        bf16x8 kf0 = __builtin_bit_cast(bf16x8, *(const uint4*)(&lds[(B)*8192 + jt*1024] + kb0)); \
        bf16x8 kf1 = __builtin_bit_cast(bf16x8, *(const uint4*)(&lds[(B)*8192 + jt*1024] + kb1)); \
        _Pragma("unroll") \
        for (int qt = 0; qt < 4; qt++){ \
          f32x4 st = {0.f,0.f,0.f,0.f}; \
          st = __builtin_amdgcn_mfma_f32_16x16x32_bf16(kf0, qf[qt][0], st, 0, 0, 0); \
          st = __builtin_amdgcn_mfma_f32_16x16x32_bf16(kf1, qf[qt][1], st, 0, 0, 0); \
          const uint32_t y0 = __float_as_uint(fmaf(st[0], 128.f, EXPMAGIC)); \
          const uint32_t y1 = __float_as_uint(fmaf(st[1], 128.f, EXPMAGIC)); \
          const uint32_t y2 = __float_as_uint(fmaf(st[2], 128.f, EXPMAGIC)); \
          const uint32_t y3 = __float_as_uint(fmaf(st[3], 128.f, EXPMAGIC)); \
          pklo[jh][qt] = __builtin_amdgcn_perm(y1, y0, 0x05040100u); \
          pkhi[jh][qt] = __builtin_amdgcn_perm(y3, y2, 0x05040100u); \
        } \
      } \
      union { uint32_t u[4]; bf16x8 f; } pf[4]; \
      _Pragma("unroll") \
      for (int qt = 0; qt < 4; qt++){ \
        pf[qt].u[0] = pklo[0][qt]; pf[qt].u[1] = pkhi[0][qt]; \
        pf[qt].u[2] = pklo[1][qt]; pf[qt].u[3] = pkhi[1][qt]; \
      } \
      __builtin_amdgcn_s_setprio(1); \
      _Pragma("unroll") \
      for (int qt = 0; qt < 4; qt++) \
        lacc[qt] = __builtin_amdgcn_mfma_f32_16x16x32_bf16(onesv, pf[qt].f, lacc[qt], 0, 0, 0); \
      _Pragma("unroll") \
      for (int dt = 0; dt < 4; dt++){ \
        union { uint64_t v[2]; bf16x8 f; } vf; \
        vf.v[0] = *(const uint64_t*)(&lds[(B)*8192 + 4096 + dt*1024] + vb[p][0]); \
        vf.v[1] = *(const uint64_t*)(&lds[(B)*8192 + 4096 + dt*1024] + vb[p][1]); \
        _Pragma("unroll") \
        for (int qt = 0; qt < 4; qt++) \
          acc[dt][qt] = __builtin_amdgcn_mfma_f32_16x16x32_bf16(vf.f, pf[qt].f, acc[dt][qt], 0, 0, 0); \
      } \
      __builtin_amdgcn_s_setprio(0); \
    } \
  }while(0)

// pair of tiles on bufs (B0,B1); optionally stage next pair into (B0^2,B1^2)
#define PAIR_T(B0, B1, STG, SYNC) do{ \
    if (STG){ STAGE_T((B0)^2); STAGE_T((B1)^2); } \
    TILE_T(B0); \
    TILE_T(B1); \
    if (SYNC){ asm volatile("s_waitcnt vmcnt(0)" ::: "memory"); __builtin_amdgcn_s_barrier(); } \
  }while(0)

  // prologue: tiles 0,1 -> bufs 0,1; fully resident before loop
  STAGE_T(0); STAGE_T(1);
  asm volatile("s_waitcnt vmcnt(0)" ::: "memory");
  __builtin_amdgcn_s_barrier();

  #pragma unroll 1
  for (int rr = 0; rr < 7; rr++){     // pairs p=0..13 (tiles 0..27)
    PAIR_T(0, 1, 1, 1);
    PAIR_T(2, 3, 1, 1);
  }
  PAIR_T(0, 1, 1, 1);                 // p=14: tiles 28,29; stages 30,31 -> bufs 2,3
  PAIR_T(2, 3, 0, 0);                 // p=15: tiles 30,31

#undef PAIR_T
#undef TILE_T
#undef STAGE_T

  float inv[4];
  #pragma unroll
  for (int qt = 0; qt < 4; qt++) inv[qt] = 1.f / lacc[qt][0];

  #pragma unroll
  for (int qt = 0; qt < 4; qt++){
    const size_t ob = (((size_t)(b*2048 + qrow0 + qt*16))*16 + h)*64;
    #pragma unroll
    for (int dt = 0; dt < 4; dt++){
      union{ u16 u[4]; uint64_t v; } pkk;
      #pragma unroll
      for (int r = 0; r < 4; r++) pkk.u[r] = f2bf(acc[dt][qt][r] * inv[qt]);
      *reinterpret_cast<uint64_t*>(O + ob + dt*16 + g*4) = pkk.v;
    }
  }
}

// ---------------- launch ----------------
extern "C" void kernel_launch(void* const* d_in, const int* in_sizes, int n_in,
                              void* d_out, int out_size, void* d_ws, size_t ws_size,
                              hipStream_t stream)
{
  const float* x  = (const float*)d_in[0];
  const float* Wq = (const float*)d_in[1];
  const float* bq = (const float*)d_in[2];
  const float* Wk = (const float*)d_in[3];
  const float* bk = (const float*)d_in[4];
  const float* Wv = (const float*)d_in[5];
  const float* bv = (const float*)d_in[6];
  const float* Wo = (const float*)d_in[7];
  const float* bo = (const float*)d_in[8];
  float* out = (float*)d_out;

  char* ws = (char*)d_ws;
  size_t off = 0;
  auto bump = [&](size_t bytes){ size_t o = off; off = (off + bytes + 255) & ~(size_t)255; return o; };
  u16*  xb   = (u16*)  (ws + bump(8388608ull*2));
  u16*  wqkv = (u16*)  (ws + bump(3145728ull*2));
  u16*  wob  = (u16*)  (ws + bump(1048576ull*2));
  float* bqkv= (float*)(ws + bump(3072ull*4));
  u16*  qws  = (u16*)  (ws + bump(8388608ull*2));
  u16*  kws  = (u16*)  (ws + bump(8388608ull*2));
  u16*  vws  = (u16*)  (ws + bump(8388608ull*2));
  u16*  att  = (u16*)  (ws + bump(8388608ull*2));

  k_prep<<<2048, 256, 0, stream>>>(
      (const float4*)x, (const float4*)Wq, (const float4*)Wk, (const float4*)Wv, (const float4*)Wo,
      (const float4*)bq, (const float4*)bk, (const float4*)bv,
      (uint64_t*)xb, (uint64_t*)wqkv, (uint64_t*)wob, (float4*)bqkv);

  gemm128x256<0><<<dim3(12, 64), 512, 0, stream>>>(xb, wqkv, bqkv, nullptr, qws, kws, vws);
  attn_k<<<512, 256, 0, stream>>>(qws, kws, vws, att);
  gemm128x256<1><<<dim3(4, 64), 512, 0, stream>>>(att, wob, bo, out, nullptr, nullptr, nullptr);
}

// Round 20
// 150.177 us; speedup vs baseline: 1.1482x; 1.0392x over previous
//
#include <hip/hip_runtime.h>
#include <stdint.h>

typedef unsigned short u16;
typedef __bf16 bf16x8 __attribute__((ext_vector_type(8)));
typedef float f32x4 __attribute__((ext_vector_type(4)));

#define QSCALE (19.5f/1024.0f * 1.44269504088896340736f)
// float-magic Schraudolph: y = fma(s,128, 2^23*1.5 + 16250) -> low16(bits(y)) = bf16bits(exp2(s))
#define EXPMAGIC 12599162.0f

__device__ __forceinline__ u16 f2bf(float f){
  uint32_t u = __float_as_uint(f);
  return (u16)((u + 0x7FFFu + ((u >> 16) & 1u)) >> 16);   // RNE
}

__device__ __forceinline__ uint64_t cvt4(float4 f){
  union{ u16 u[4]; uint64_t v; } pk;
  pk.u[0]=f2bf(f.x); pk.u[1]=f2bf(f.y); pk.u[2]=f2bf(f.z); pk.u[3]=f2bf(f.w);
  return pk.v;
}

#define GLD_LDS16(g,l) __builtin_amdgcn_global_load_lds( \
    (const __attribute__((address_space(1))) void*)(g),  \
    (__attribute__((address_space(3))) void*)(l), 16, 0, 0)

// ---------------- fused prep ----------------
__global__ __launch_bounds__(256) void k_prep(
    const float4* __restrict__ x,  const float4* __restrict__ Wq,
    const float4* __restrict__ Wk, const float4* __restrict__ Wv,
    const float4* __restrict__ Wo,
    const float4* __restrict__ bq, const float4* __restrict__ bk, const float4* __restrict__ bv,
    uint64_t* __restrict__ xb, uint64_t* __restrict__ wqkv, uint64_t* __restrict__ wob,
    float4* __restrict__ bqkv)
{
  const int NX = 2097152, NW = 262144;
  const int total = NX + 4*NW + 768;
  int i = blockIdx.x*256 + threadIdx.x;
  const int stride = gridDim.x*256;
  for (; i < total; i += stride){
    if (i < NX)             xb[i] = cvt4(x[i]);
    else if (i < NX+NW)     { int j = i-NX;      wqkv[j]      = cvt4(Wq[j]); }
    else if (i < NX+2*NW)   { int j = i-NX-NW;   wqkv[NW+j]   = cvt4(Wk[j]); }
    else if (i < NX+3*NW)   { int j = i-NX-2*NW; wqkv[2*NW+j] = cvt4(Wv[j]); }
    else if (i < NX+4*NW)   { int j = i-NX-3*NW; wob[j]       = cvt4(Wo[j]); }
    else {
      int j = i - NX - 4*NW;
      bqkv[j] = (j < 256) ? bq[j] : (j < 512 ? bk[j-256] : bv[j-512]);
    }
  }
}

// ---------------- 128x256 bf16 GEMM: 8 waves (2Mx4N), wave-tile 64x64 ----------------
// BK=32, 3-ring (72KB -> 2 blocks/CU), stage-2-ahead, counted vmcnt(3).
// XCD-chunked grid (1D): xcd=flat&7, idx=flat>>3; mt=xcd*8+(idx&7); nt=idx>>3.
// Each XCD reuses 8 A-panels (2MB, L2-resident) across all nt.
// MODE 0: QKV projection (768 blocks); MODE 1: output projection -> fp32 (256 blocks).
// Balanced swizzle: LDS[row][c] = global[row][c ^ ((row>>1)&3)].
template<int MODE>
__global__ __launch_bounds__(512) void gemm128x256(
    const u16* __restrict__ A, const u16* __restrict__ Bw,
    const float* __restrict__ bias, float* __restrict__ Cout,
    u16* __restrict__ q_ws, u16* __restrict__ k_ws, u16* __restrict__ v_ws)
{
  __shared__ u16 lds[3*12288];   // [buf:3][ A:128x32 (4096 u16) | B:256x32 (8192 u16) ]
  const int tid  = threadIdx.x;
  const int w    = tid >> 6, lane = tid & 63;
  const int wr   = w >> 2,  wc   = w & 3;
  const int g    = lane >> 4, c16 = lane & 15;

  const int flat = blockIdx.x;
  const int xcd  = flat & 7, idx = flat >> 3;
  const int mt   = xcd*8 + (idx & 7);
  const int nt   = idx >> 3;
  const size_t arow0 = (size_t)mt * 128, brow0 = (size_t)nt * 256;

  f32x4 acc[4][4] = {};

  const int schk = ((tid & 3) ^ ((tid >> 3) & 3)) * 8;
  const u16* gA = A  + (arow0 + (tid >> 2))*1024 + schk;
  const u16* gB = Bw + (brow0 + (tid >> 2))*1024 + schk;

  const int rswz = (g ^ ((c16 >> 1) & 3)) * 8;
  const int abase = (wr*64 + c16)*32 + rswz;
  const int bbase = 4096 + (wc*64 + c16)*32 + rswz;

#define GSTAGE(B2) do{ \
    GLD_LDS16(gA,           &lds[(B2)*12288 +        tid*8]); \
    GLD_LDS16(gB,           &lds[(B2)*12288 + 4096 + tid*8]); \
    GLD_LDS16(gB + 131072,  &lds[(B2)*12288 + 8192 + tid*8]); \
    gA += 32; gB += 32; \
  }while(0)

#define GBODY(B, STG, VMW) do{ \
    if (STG) GSTAGE(((B)+2)%3); \
    bf16x8 af[4], bfr[4]; \
    _Pragma("unroll") \
    for (int m = 0; m < 4; m++) \
      af[m]  = __builtin_bit_cast(bf16x8, *(const uint4*)(&lds[(B)*12288 + abase + m*512])); \
    _Pragma("unroll") \
    for (int n = 0; n < 4; n++) \
      bfr[n] = __builtin_bit_cast(bf16x8, *(const uint4*)(&lds[(B)*12288 + bbase + n*512])); \
    __builtin_amdgcn_s_setprio(1); \
    _Pragma("unroll") \
    for (int m = 0; m < 4; m++) \
      _Pragma("unroll") \
      for (int n = 0; n < 4; n++) \
        acc[m][n] = __builtin_amdgcn_mfma_f32_16x16x32_bf16(af[m], bfr[n], acc[m][n], 0, 0, 0); \
    __builtin_amdgcn_s_setprio(0); \
    if ((VMW) == 3){ asm volatile("s_waitcnt vmcnt(3)" ::: "memory"); __builtin_amdgcn_s_barrier(); } \
    else if ((VMW) == 0){ asm volatile("s_waitcnt vmcnt(0)" ::: "memory"); __builtin_amdgcn_s_barrier(); } \
  }while(0)

  GSTAGE(0); GSTAGE(1);
  asm volatile("s_waitcnt vmcnt(3)" ::: "memory");
  __builtin_amdgcn_s_barrier();

  #pragma unroll 1
  for (int rr = 0; rr < 10; rr++){
    GBODY(0, 1, 3);
    GBODY(1, 1, 3);
    GBODY(2, 1, 3);
  }
  GBODY(0, 0, 0);
  GBODY(1, 0, -1);

#undef GBODY
#undef GSTAGE

  #pragma unroll
  for (int m = 0; m < 4; m++){
    const size_t i0 = arow0 + wr*64 + m*16 + g*4;
    #pragma unroll
    for (int n = 0; n < 4; n++){
      const int o = (int)brow0 + wc*64 + n*16 + c16;
      const float bias_v = bias[o];
      if (MODE == 0){
        const int proj = o >> 10, wi = o & 1023, hh = wi >> 6, dd = wi & 63;
        if (proj < 2){
          u16* base = (proj == 0) ? q_ws : k_ws;
          const float sc = (proj == 0) ? QSCALE : 1.0f;
          #pragma unroll
          for (int r = 0; r < 4; r++){
            const size_t i = i0 + r;
            const size_t bb = i >> 11, nn = i & 2047;
            base[((bb*16 + hh)*2048 + nn)*64 + dd] = f2bf((acc[m][n][r] + bias_v)*sc);
          }
        } else {
          const size_t bb = i0 >> 11, nn = i0 & 2047;
          union{ u16 u[4]; uint64_t v; } pk;
          #pragma unroll
          for (int r = 0; r < 4; r++) pk.u[r] = f2bf(acc[m][n][r] + bias_v);
          *reinterpret_cast<uint64_t*>(v_ws + ((bb*16 + hh)*64 + dd)*2048 + nn) = pk.v;
        }
      } else {
        #pragma unroll
        for (int r = 0; r < 4; r++)
          Cout[(i0 + r)*1024 + o] = acc[m][n][r] + bias_v;
      }
    }
  }
}

// ---------------- flash attention: 4-ring, paired tiles, barrier every 2 tiles ----------------
__global__ __launch_bounds__(256, 2) void attn_k(
    const u16* __restrict__ Q, const u16* __restrict__ Kb, const u16* __restrict__ Vt,
    u16* __restrict__ O)
{
  __shared__ u16 lds[4*8192];   // [buf:4][ K:4096 | V:4096 ], XOR-8 swizzled 16B slots
  const int tid = threadIdx.x, w = tid >> 6, lane = tid & 63;
  const int g = lane >> 4, l16 = lane & 15;

  const int f   = ((blockIdx.x & 7) << 6) | (blockIdx.x >> 3);
  const int qt_ = f & 7, bh = f >> 3;
  const int b = bh >> 4, h = bh & 15;
  const size_t hb = (size_t)bh * 2048 * 64;

  const int qrow0 = qt_*256 + w*64 + l16;
  bf16x8 qf[4][2];
  #pragma unroll
  for (int qt = 0; qt < 4; qt++)
    #pragma unroll
    for (int kc = 0; kc < 2; kc++)
      qf[qt][kc] = __builtin_bit_cast(bf16x8,
        *(const uint4*)(Q + hb + (size_t)(qrow0 + qt*16)*64 + kc*32 + g*8));

  f32x4 acc[4][4] = {};
  f32x4 lacc[4] = {};

  union{ u16 u[8]; bf16x8 f; } one_;
  #pragma unroll
  for (int i = 0; i < 8; i++) one_.u[i] = 0x3F80;
  const bf16x8 onesv = one_.f;

  const int srowL = w*8 + (lane >> 3);
  const int schunk = ((lane & 7) ^ ((lane >> 3) & 7)) * 8;
  const u16* gKs = Kb + hb + (size_t)srowL*64   + schunk;
  const u16* gVs = Vt + hb + (size_t)srowL*2048 + schunk;

  u16* ldsK0 = &lds[w*512];
  u16* ldsV0 = &lds[4096 + w*512];

  const int kb0 = l16*64 + (g ^ (l16 & 7))*8;
  const int kb1 = kb0 ^ 32;
  const int vswz = l16 & 7, vlo = (g & 1)*4, vg2 = g >> 1;
  int vb[2][2];
  #pragma unroll
  for (int p = 0; p < 2; p++)
    #pragma unroll
    for (int pc = 0; pc < 2; pc++)
      vb[p][pc] = l16*64 + (((p*4 + pc*2 + vg2) ^ vswz) << 3) + vlo;

#define STAGE_T(B2) do{ \
    GLD_LDS16(gKs,          ldsK0 + (B2)*8192); \
    GLD_LDS16(gKs + 2048,   ldsK0 + (B2)*8192 + 2048); \
    GLD_LDS16(gVs,          ldsV0 + (B2)*8192); \
    GLD_LDS16(gVs + 65536,  ldsV0 + (B2)*8192 + 2048); \
    gKs += 4096; gVs += 64; \
  }while(0)

#define TILE_T(B) do{ \
    _Pragma("unroll") \
    for (int p = 0; p < 2; p++){ \
      uint32_t pklo[2][4], pkhi[2][4]; \
      _Pragma("unroll") \
      for (int jh = 0; jh < 2; jh++){ \
        const int jt = p*2 + jh; \
        bf16x8 kf0 = __builtin_bit_cast(bf16x8, *(const uint4*)(&lds[(B)*8192 + jt*1024] + kb0)); \
        bf16x8 kf1 = __builtin_bit_cast(bf16x8, *(const uint4*)(&lds[(B)*8192 + jt*1024] + kb1)); \
        _Pragma("unroll") \
        for (int qt = 0; qt < 4; qt++){ \
          f32x4 st = {0.f,0.f,0.f,0.f}; \
          st = __builtin_amdgcn_mfma_f32_16x16x32_bf16(kf0, qf[qt][0], st, 0, 0, 0); \
          st = __builtin_amdgcn_mfma_f32_16x16x32_bf16(kf1, qf[qt][1], st, 0, 0, 0); \
          const uint32_t y0 = __float_as_uint(fmaf(st[0], 128.f, EXPMAGIC)); \
          const uint32_t y1 = __float_as_uint(fmaf(st[1], 128.f, EXPMAGIC)); \
          const uint32_t y2 = __float_as_uint(fmaf(st[2], 128.f, EXPMAGIC)); \
          const uint32_t y3 = __float_as_uint(fmaf(st[3], 128.f, EXPMAGIC)); \
          pklo[jh][qt] = __builtin_amdgcn_perm(y1, y0, 0x05040100u); \
          pkhi[jh][qt] = __builtin_amdgcn_perm(y3, y2, 0x05040100u); \
        } \
      } \
      union { uint32_t u[4]; bf16x8 f; } pf[4]; \
      _Pragma("unroll") \
      for (int qt = 0; qt < 4; qt++){ \
        pf[qt].u[0] = pklo[0][qt]; pf[qt].u[1] = pkhi[0][qt]; \
        pf[qt].u[2] = pklo[1][qt]; pf[qt].u[3] = pkhi[1][qt]; \
      } \
      __builtin_amdgcn_s_setprio(1); \
      _Pragma("unroll") \
      for (int qt = 0; qt < 4; qt++) \
        lacc[qt] = __builtin_amdgcn_mfma_f32_16x16x32_bf16(onesv, pf[qt].f, lacc[qt], 0, 0, 0); \
      _Pragma("unroll") \
      for (int dt = 0; dt < 4; dt++){ \
        union { uint64_t v[2]; bf16x8 f; } vf; \
        vf.v[0] = *(const uint64_t*)(&lds[(B)*8192 + 4096 + dt*1024] + vb[p][0]); \
        vf.v[1] = *(const uint64_t*)(&lds[(B)*8192 + 4096 + dt*1024] + vb[p][1]); \
        _Pragma("unroll") \
        for (int qt = 0; qt < 4; qt++) \
          acc[dt][qt] = __builtin_amdgcn_mfma_f32_16x16x32_bf16(vf.f, pf[qt].f, acc[dt][qt], 0, 0, 0); \
      } \
      __builtin_amdgcn_s_setprio(0); \
    } \
  }while(0)

#define PAIR_T(B0, B1, STG, SYNC) do{ \
    if (STG){ STAGE_T((B0)^2); STAGE_T((B1)^2); } \
    TILE_T(B0); \
    TILE_T(B1); \
    if (SYNC){ asm volatile("s_waitcnt vmcnt(0)" ::: "memory"); __builtin_amdgcn_s_barrier(); } \
  }while(0)

  STAGE_T(0); STAGE_T(1);
  asm volatile("s_waitcnt vmcnt(0)" ::: "memory");
  __builtin_amdgcn_s_barrier();

  #pragma unroll 1
  for (int rr = 0; rr < 7; rr++){
    PAIR_T(0, 1, 1, 1);
    PAIR_T(2, 3, 1, 1);
  }
  PAIR_T(0, 1, 1, 1);
  PAIR_T(2, 3, 0, 0);

#undef PAIR_T
#undef TILE_T
#undef STAGE_T

  float inv[4];
  #pragma unroll
  for (int qt = 0; qt < 4; qt++) inv[qt] = 1.f / lacc[qt][0];

  #pragma unroll
  for (int qt = 0; qt < 4; qt++){
    const size_t ob = (((size_t)(b*2048 + qrow0 + qt*16))*16 + h)*64;
    #pragma unroll
    for (int dt = 0; dt < 4; dt++){
      union{ u16 u[4]; uint64_t v; } pkk;
      #pragma unroll
      for (int r = 0; r < 4; r++) pkk.u[r] = f2bf(acc[dt][qt][r] * inv[qt]);
      *reinterpret_cast<uint64_t*>(O + ob + dt*16 + g*4) = pkk.v;
    }
  }
}

// ---------------- launch ----------------
extern "C" void kernel_launch(void* const* d_in, const int* in_sizes, int n_in,
                              void* d_out, int out_size, void* d_ws, size_t ws_size,
                              hipStream_t stream)
{
  const float* x  = (const float*)d_in[0];
  const float* Wq = (const float*)d_in[1];
  const float* bq = (const float*)d_in[2];
  const float* Wk = (const float*)d_in[3];
  const float* bk = (const float*)d_in[4];
  const float* Wv = (const float*)d_in[5];
  const float* bv = (const float*)d_in[6];
  const float* Wo = (const float*)d_in[7];
  const float* bo = (const float*)d_in[8];
  float* out = (float*)d_out;

  char* ws = (char*)d_ws;
  size_t off = 0;
  auto bump = [&](size_t bytes){ size_t o = off; off = (off + bytes + 255) & ~(size_t)255; return o; };
  u16*  xb   = (u16*)  (ws + bump(8388608ull*2));
  u16*  wqkv = (u16*)  (ws + bump(3145728ull*2));
  u16*  wob  = (u16*)  (ws + bump(1048576ull*2));
  float* bqkv= (float*)(ws + bump(3072ull*4));
  u16*  qws  = (u16*)  (ws + bump(8388608ull*2));
  u16*  kws  = (u16*)  (ws + bump(8388608ull*2));
  u16*  vws  = (u16*)  (ws + bump(8388608ull*2));
  u16*  att  = (u16*)  (ws + bump(8388608ull*2));

  k_prep<<<2048, 256, 0, stream>>>(
      (const float4*)x, (const float4*)Wq, (const float4*)Wk, (const float4*)Wv, (const float4*)Wo,
      (const float4*)bq, (const float4*)bk, (const float4*)bv,
      (uint64_t*)xb, (uint64_t*)wqkv, (uint64_t*)wob, (float4*)bqkv);

  gemm128x256<0><<<768, 512, 0, stream>>>(xb, wqkv, bqkv, nullptr, qws, kws, vws);
  attn_k<<<512, 256, 0, stream>>>(qws, kws, vws, att);
  gemm128x256<1><<<256, 512, 0, stream>>>(att, wob, bo, out, nullptr, nullptr, nullptr);
}

// Round 21
// 148.512 us; speedup vs baseline: 1.1611x; 1.0112x over previous
//
#include <hip/hip_runtime.h>
#include <stdint.h>

typedef unsigned short u16;
typedef __bf16 bf16x8 __attribute__((ext_vector_type(8)));
typedef float f32x4 __attribute__((ext_vector_type(4)));

#define QSCALE (19.5f/1024.0f * 1.44269504088896340736f)
// float-magic Schraudolph: y = fma(s,128, 2^23*1.5 + 16250) -> low16(bits(y)) = bf16bits(exp2(s))
#define EXPMAGIC 12599162.0f

__device__ __forceinline__ u16 f2bf(float f){
  uint32_t u = __float_as_uint(f);
  return (u16)((u + 0x7FFFu + ((u >> 16) & 1u)) >> 16);   // RNE
}

__device__ __forceinline__ uint64_t cvt4(float4 f){
  union{ u16 u[4]; uint64_t v; } pk;
  pk.u[0]=f2bf(f.x); pk.u[1]=f2bf(f.y); pk.u[2]=f2bf(f.z); pk.u[3]=f2bf(f.w);
  return pk.v;
}

#define GLD_LDS16(g,l) __builtin_amdgcn_global_load_lds( \
    (const __attribute__((address_space(1))) void*)(g),  \
    (__attribute__((address_space(3))) void*)(l), 16, 0, 0)

// ---------------- fused prep ----------------
__global__ __launch_bounds__(256) void k_prep(
    const float4* __restrict__ x,  const float4* __restrict__ Wq,
    const float4* __restrict__ Wk, const float4* __restrict__ Wv,
    const float4* __restrict__ Wo,
    const float4* __restrict__ bq, const float4* __restrict__ bk, const float4* __restrict__ bv,
    uint64_t* __restrict__ xb, uint64_t* __restrict__ wqkv, uint64_t* __restrict__ wob,
    float4* __restrict__ bqkv)
{
  const int NX = 2097152, NW = 262144;
  const int total = NX + 4*NW + 768;
  int i = blockIdx.x*256 + threadIdx.x;
  const int stride = gridDim.x*256;
  for (; i < total; i += stride){
    if (i < NX)             xb[i] = cvt4(x[i]);
    else if (i < NX+NW)     { int j = i-NX;      wqkv[j]      = cvt4(Wq[j]); }
    else if (i < NX+2*NW)   { int j = i-NX-NW;   wqkv[NW+j]   = cvt4(Wk[j]); }
    else if (i < NX+3*NW)   { int j = i-NX-2*NW; wqkv[2*NW+j] = cvt4(Wv[j]); }
    else if (i < NX+4*NW)   { int j = i-NX-3*NW; wob[j]       = cvt4(Wo[j]); }
    else {
      int j = i - NX - 4*NW;
      bqkv[j] = (j < 256) ? bq[j] : (j < 512 ? bk[j-256] : bv[j-512]);
    }
  }
}

// ---------------- 128x256 bf16 GEMM: 8 waves (2Mx4N), wave-tile 64x64 ----------------
// BK=32, 3-ring (72KB -> 2 blocks/CU), stage-2-ahead, counted vmcnt(3).
// XCD-chunked grid (1D): xcd=flat&7, idx=flat>>3; mt=xcd*8+(idx&7); nt=idx>>3.
// MODE 0: QKV projection (768 blocks); V^T written in bijection-order n'
//   (n' = r | hi<<2 | g<<3 within each 32-run) so attn PV fragments are contiguous 16B.
// MODE 1: output projection -> fp32 (256 blocks).
// Balanced swizzle: LDS[row][c] = global[row][c ^ ((row>>1)&3)].
template<int MODE>
__global__ __launch_bounds__(512) void gemm128x256(
    const u16* __restrict__ A, const u16* __restrict__ Bw,
    const float* __restrict__ bias, float* __restrict__ Cout,
    u16* __restrict__ q_ws, u16* __restrict__ k_ws, u16* __restrict__ v_ws)
{
  __shared__ u16 lds[3*12288];   // [buf:3][ A:128x32 (4096 u16) | B:256x32 (8192 u16) ]
  const int tid  = threadIdx.x;
  const int w    = tid >> 6, lane = tid & 63;
  const int wr   = w >> 2,  wc   = w & 3;
  const int g    = lane >> 4, c16 = lane & 15;

  const int flat = blockIdx.x;
  const int xcd  = flat & 7, idx = flat >> 3;
  const int mt   = xcd*8 + (idx & 7);
  const int nt   = idx >> 3;
  const size_t arow0 = (size_t)mt * 128, brow0 = (size_t)nt * 256;

  f32x4 acc[4][4] = {};

  const int schk = ((tid & 3) ^ ((tid >> 3) & 3)) * 8;
  const u16* gA = A  + (arow0 + (tid >> 2))*1024 + schk;
  const u16* gB = Bw + (brow0 + (tid >> 2))*1024 + schk;

  const int rswz = (g ^ ((c16 >> 1) & 3)) * 8;
  const int abase = (wr*64 + c16)*32 + rswz;
  const int bbase = 4096 + (wc*64 + c16)*32 + rswz;

#define GSTAGE(B2) do{ \
    GLD_LDS16(gA,           &lds[(B2)*12288 +        tid*8]); \
    GLD_LDS16(gB,           &lds[(B2)*12288 + 4096 + tid*8]); \
    GLD_LDS16(gB + 131072,  &lds[(B2)*12288 + 8192 + tid*8]); \
    gA += 32; gB += 32; \
  }while(0)

#define GBODY(B, STG, VMW) do{ \
    if (STG) GSTAGE(((B)+2)%3); \
    bf16x8 af[4], bfr[4]; \
    _Pragma("unroll") \
    for (int m = 0; m < 4; m++) \
      af[m]  = __builtin_bit_cast(bf16x8, *(const uint4*)(&lds[(B)*12288 + abase + m*512])); \
    _Pragma("unroll") \
    for (int n = 0; n < 4; n++) \
      bfr[n] = __builtin_bit_cast(bf16x8, *(const uint4*)(&lds[(B)*12288 + bbase + n*512])); \
    __builtin_amdgcn_s_setprio(1); \
    _Pragma("unroll") \
    for (int m = 0; m < 4; m++) \
      _Pragma("unroll") \
      for (int n = 0; n < 4; n++) \
        acc[m][n] = __builtin_amdgcn_mfma_f32_16x16x32_bf16(af[m], bfr[n], acc[m][n], 0, 0, 0); \
    __builtin_amdgcn_s_setprio(0); \
    if ((VMW) == 3){ asm volatile("s_waitcnt vmcnt(3)" ::: "memory"); __builtin_amdgcn_s_barrier(); } \
    else if ((VMW) == 0){ asm volatile("s_waitcnt vmcnt(0)" ::: "memory"); __builtin_amdgcn_s_barrier(); } \
  }while(0)

  GSTAGE(0); GSTAGE(1);
  asm volatile("s_waitcnt vmcnt(3)" ::: "memory");
  __builtin_amdgcn_s_barrier();

  #pragma unroll 1
  for (int rr = 0; rr < 10; rr++){
    GBODY(0, 1, 3);
    GBODY(1, 1, 3);
    GBODY(2, 1, 3);
  }
  GBODY(0, 0, 0);
  GBODY(1, 0, -1);

#undef GBODY
#undef GSTAGE

  #pragma unroll
  for (int m = 0; m < 4; m++){
    const size_t i0 = arow0 + wr*64 + m*16 + g*4;
    #pragma unroll
    for (int n = 0; n < 4; n++){
      const int o = (int)brow0 + wc*64 + n*16 + c16;
      const float bias_v = bias[o];
      if (MODE == 0){
        const int proj = o >> 10, wi = o & 1023, hh = wi >> 6, dd = wi & 63;
        if (proj < 2){
          u16* base = (proj == 0) ? q_ws : k_ws;
          const float sc = (proj == 0) ? QSCALE : 1.0f;
          #pragma unroll
          for (int r = 0; r < 4; r++){
            const size_t i = i0 + r;
            const size_t bb = i >> 11, nn = i & 2047;
            base[((bb*16 + hh)*2048 + nn)*64 + dd] = f2bf((acc[m][n][r] + bias_v)*sc);
          }
        } else {
          // V^T in bijection-order: within each 32-run of n (4-aligned nn -> r bits = 0):
          // n' = (nn & ~31) | ((nn>>4)&1)<<2 | ((nn>>2)&3)<<3
          const size_t bb = i0 >> 11;
          const uint32_t nn = (uint32_t)(i0 & 2047);
          const uint32_t nnp = (nn & ~31u) | (((nn >> 4) & 1u) << 2) | (((nn >> 2) & 3u) << 3);
          union{ u16 u[4]; uint64_t v; } pk;
          #pragma unroll
          for (int r = 0; r < 4; r++) pk.u[r] = f2bf(acc[m][n][r] + bias_v);
          *reinterpret_cast<uint64_t*>(v_ws + ((bb*16 + hh)*64 + dd)*2048 + nnp) = pk.v;
        }
      } else {
        #pragma unroll
        for (int r = 0; r < 4; r++)
          Cout[(i0 + r)*1024 + o] = acc[m][n][r] + bias_v;
      }
    }
  }
}

// ---------------- flash attention: 4-ring, paired tiles; V reads single b128 ----------------
__global__ __launch_bounds__(256, 2) void attn_k(
    const u16* __restrict__ Q, const u16* __restrict__ Kb, const u16* __restrict__ Vt,
    u16* __restrict__ O)
{
  __shared__ u16 lds[4*8192];   // [buf:4][ K:4096 | V:4096 ], XOR-8 swizzled 16B slots
  const int tid = threadIdx.x, w = tid >> 6, lane = tid & 63;
  const int g = lane >> 4, l16 = lane & 15;

  const int f   = ((blockIdx.x & 7) << 6) | (blockIdx.x >> 3);
  const int qt_ = f & 7, bh = f >> 3;
  const int b = bh >> 4, h = bh & 15;
  const size_t hb = (size_t)bh * 2048 * 64;

  const int qrow0 = qt_*256 + w*64 + l16;
  bf16x8 qf[4][2];
  #pragma unroll
  for (int qt = 0; qt < 4; qt++)
    #pragma unroll
    for (int kc = 0; kc < 2; kc++)
      qf[qt][kc] = __builtin_bit_cast(bf16x8,
        *(const uint4*)(Q + hb + (size_t)(qrow0 + qt*16)*64 + kc*32 + g*8));

  f32x4 acc[4][4] = {};
  f32x4 lacc[4] = {};

  union{ u16 u[8]; bf16x8 f; } one_;
  #pragma unroll
  for (int i = 0; i < 8; i++) one_.u[i] = 0x3F80;
  const bf16x8 onesv = one_.f;

  const int srowL = w*8 + (lane >> 3);
  const int schunk = ((lane & 7) ^ ((lane >> 3) & 7)) * 8;
  const u16* gKs = Kb + hb + (size_t)srowL*64   + schunk;
  const u16* gVs = Vt + hb + (size_t)srowL*2048 + schunk;

  u16* ldsK0 = &lds[w*512];
  u16* ldsV0 = &lds[4096 + w*512];

  const int kb0 = l16*64 + (g ^ (l16 & 7))*8;
  const int kb1 = kb0 ^ 32;
  // V fragment (bijection-order layout): single b128 at chunk (p*4+g)^(l16&7)
  int vbp[2];
  #pragma unroll
  for (int p = 0; p < 2; p++)
    vbp[p] = l16*64 + (((p*4 + g) ^ (l16 & 7)) << 3);

#define STAGE_T(B2) do{ \
    GLD_LDS16(gKs,          ldsK0 + (B2)*8192); \
    GLD_LDS16(gKs + 2048,   ldsK0 + (B2)*8192 + 2048); \
    GLD_LDS16(gVs,          ldsV0 + (B2)*8192); \
    GLD_LDS16(gVs + 65536,  ldsV0 + (B2)*8192 + 2048); \
    gKs += 4096; gVs += 64; \
  }while(0)

#define TILE_T(B) do{ \
    _Pragma("unroll") \
    for (int p = 0; p < 2; p++){ \
      uint32_t pklo[2][4], pkhi[2][4]; \
      _Pragma("unroll") \
      for (int jh = 0; jh < 2; jh++){ \
        const int jt = p*2 + jh; \
        bf16x8 kf0 = __builtin_bit_cast(bf16x8, *(const uint4*)(&lds[(B)*8192 + jt*1024] + kb0)); \
        bf16x8 kf1 = __builtin_bit_cast(bf16x8, *(const uint4*)(&lds[(B)*8192 + jt*1024] + kb1)); \
        _Pragma("unroll") \
        for (int qt = 0; qt < 4; qt++){ \
          f32x4 st = {0.f,0.f,0.f,0.f}; \
          st = __builtin_amdgcn_mfma_f32_16x16x32_bf16(kf0, qf[qt][0], st, 0, 0, 0); \
          st = __builtin_amdgcn_mfma_f32_16x16x32_bf16(kf1, qf[qt][1], st, 0, 0, 0); \
          const uint32_t y0 = __float_as_uint(fmaf(st[0], 128.f, EXPMAGIC)); \
          const uint32_t y1 = __float_as_uint(fmaf(st[1], 128.f, EXPMAGIC)); \
          const uint32_t y2 = __float_as_uint(fmaf(st[2], 128.f, EXPMAGIC)); \
          const uint32_t y3 = __float_as_uint(fmaf(st[3], 128.f, EXPMAGIC)); \
          pklo[jh][qt] = __builtin_amdgcn_perm(y1, y0, 0x05040100u); \
          pkhi[jh][qt] = __builtin_amdgcn_perm(y3, y2, 0x05040100u); \
        } \
      } \
      union { uint32_t u[4]; bf16x8 f; } pf[4]; \
      _Pragma("unroll") \
      for (int qt = 0; qt < 4; qt++){ \
        pf[qt].u[0] = pklo[0][qt]; pf[qt].u[1] = pkhi[0][qt]; \
        pf[qt].u[2] = pklo[1][qt]; pf[qt].u[3] = pkhi[1][qt]; \
      } \
      __builtin_amdgcn_s_setprio(1); \
      _Pragma("unroll") \
      for (int qt = 0; qt < 4; qt++) \
        lacc[qt] = __builtin_amdgcn_mfma_f32_16x16x32_bf16(onesv, pf[qt].f, lacc[qt], 0, 0, 0); \
      _Pragma("unroll") \
      for (int dt = 0; dt < 4; dt++){ \
        union { uint4 u4; bf16x8 f; } vf; \
        vf.u4 = *(const uint4*)(&lds[(B)*8192 + 4096 + dt*1024] + vbp[p]); \
        _Pragma("unroll") \
        for (int qt = 0; qt < 4; qt++) \
          acc[dt][qt] = __builtin_amdgcn_mfma_f32_16x16x32_bf16(vf.f, pf[qt].f, acc[dt][qt], 0, 0, 0); \
      } \
      __builtin_amdgcn_s_setprio(0); \
    } \
  }while(0)

#define PAIR_T(B0, B1, STG, SYNC) do{ \
    if (STG){ STAGE_T((B0)^2); STAGE_T((B1)^2); } \
    TILE_T(B0); \
    TILE_T(B1); \
    if (SYNC){ asm volatile("s_waitcnt vmcnt(0)" ::: "memory"); __builtin_amdgcn_s_barrier(); } \
  }while(0)

  STAGE_T(0); STAGE_T(1);
  asm volatile("s_waitcnt vmcnt(0)" ::: "memory");
  __builtin_amdgcn_s_barrier();

  #pragma unroll 1
  for (int rr = 0; rr < 7; rr++){
    PAIR_T(0, 1, 1, 1);
    PAIR_T(2, 3, 1, 1);
  }
  PAIR_T(0, 1, 1, 1);
  PAIR_T(2, 3, 0, 0);

#undef PAIR_T
#undef TILE_T
#undef STAGE_T

  float inv[4];
  #pragma unroll
  for (int qt = 0; qt < 4; qt++) inv[qt] = 1.f / lacc[qt][0];

  #pragma unroll
  for (int qt = 0; qt < 4; qt++){
    const size_t ob = (((size_t)(b*2048 + qrow0 + qt*16))*16 + h)*64;
    #pragma unroll
    for (int dt = 0; dt < 4; dt++){
      union{ u16 u[4]; uint64_t v; } pkk;
      #pragma unroll
      for (int r = 0; r < 4; r++) pkk.u[r] = f2bf(acc[dt][qt][r] * inv[qt]);
      *reinterpret_cast<uint64_t*>(O + ob + dt*16 + g*4) = pkk.v;
    }
  }
}

// ---------------- launch ----------------
extern "C" void kernel_launch(void* const* d_in, const int* in_sizes, int n_in,
                              void* d_out, int out_size, void* d_ws, size_t ws_size,
                              hipStream_t stream)
{
  const float* x  = (const float*)d_in[0];
  const float* Wq = (const float*)d_in[1];
  const float* bq = (const float*)d_in[2];
  const float* Wk = (const float*)d_in[3];
  const float* bk = (const float*)d_in[4];
  const float* Wv = (const float*)d_in[5];
  const float* bv = (const float*)d_in[6];
  const float* Wo = (const float*)d_in[7];
  const float* bo = (const float*)d_in[8];
  float* out = (float*)d_out;

  char* ws = (char*)d_ws;
  size_t off = 0;
  auto bump = [&](size_t bytes){ size_t o = off; off = (off + bytes + 255) & ~(size_t)255; return o; };
  u16*  xb   = (u16*)  (ws + bump(8388608ull*2));
  u16*  wqkv = (u16*)  (ws + bump(3145728ull*2));
  u16*  wob  = (u16*)  (ws + bump(1048576ull*2));
  float* bqkv= (float*)(ws + bump(3072ull*4));
  u16*  qws  = (u16*)  (ws + bump(8388608ull*2));
  u16*  kws  = (u16*)  (ws + bump(8388608ull*2));
  u16*  vws  = (u16*)  (ws + bump(8388608ull*2));
  u16*  att  = (u16*)  (ws + bump(8388608ull*2));

  k_prep<<<2048, 256, 0, stream>>>(
      (const float4*)x, (const float4*)Wq, (const float4*)Wk, (const float4*)Wv, (const float4*)Wo,
      (const float4*)bq, (const float4*)bk, (const float4*)bv,
      (uint64_t*)xb, (uint64_t*)wqkv, (uint64_t*)wob, (float4*)bqkv);

  gemm128x256<0><<<768, 512, 0, stream>>>(xb, wqkv, bqkv, nullptr, qws, kws, vws);
  attn_k<<<512, 256, 0, stream>>>(qws, kws, vws, att);
  gemm128x256<1><<<256, 512, 0, stream>>>(att, wob, bo, out, nullptr, nullptr, nullptr);
}